// Round 3
// baseline (387.798 us; speedup 1.0000x reference)
//
#include <hip/hip_runtime.h>

#define HH 1024
#define WW 1024
#define BH 64              // output rows per block -> 16 strips x 48 images = 768 blocks
#define RAD 4
#define NSTRIP (HH / BH)   // 16, power of two

struct HS { float h0, h1, h2, h3; };

// 9-wide clipped horizontal sums for 4 consecutive columns from 3 overlapping
// float4 loads (L1/L2 absorb the 3x request amplification).
__device__ __forceinline__ HS hcompute(float4 a, float4 b, float4 d) {
    HS h;
    h.h0 = ((a.x + a.y) + (a.z + a.w)) + ((b.x + b.y) + (b.z + b.w)) + d.x;
    h.h1 = h.h0 - a.x + d.y;
    h.h2 = h.h1 - a.y + d.z;
    h.h3 = h.h2 - a.z + d.w;
    return h;
}

#define LOADROW(pa, pb, pd, rowptr) do {                                   \
    pb = *(const float4*)((rowptr) + c);                                   \
    pa = first ? z4 : *(const float4*)((rowptr) + c - 4);                  \
    pd = last  ? z4 : *(const float4*)((rowptr) + c + 4);                  \
} while (0)

// Pipelined interior step: consume prefetch set PX (holds row r+4), then
// immediately re-issue PX for row r+7 (3 steps ahead -> ~3 steps of latency
// hiding, carried across the chunk-loop back-edge in registers).
// J = ring slot (static), PX = prefetch set (static, = (r-r0)%3).
#define PSTEP(J, PX) do {                                                  \
    HS h = hcompute(pa##PX, pb##PX, pd##PX);                               \
    LOADROW(pa##PX, pb##PX, pd##PX, rowp); rowp += WW;                     \
    vs0 += h.h0 - ring[J].h0;                                              \
    vs1 += h.h1 - ring[J].h1;                                              \
    vs2 += h.h2 - ring[J].h2;                                              \
    vs3 += h.h3 - ring[J].h3;                                              \
    ring[J] = h;                                                           \
    *(float4*)(op + c) = make_float4(vs0 * w0, vs1 * w1, vs2 * w2, vs3 * w3); \
    op += WW;                                                              \
} while (0)

// Generic (boundary-strip) step with row clipping; 2 of 16 strips only.
#define GSTEP(J) do {                                                      \
    int rl = r + RAD;                                                      \
    HS h;                                                                  \
    if (rl < HH) {                                                         \
        float4 a, b, d;                                                    \
        LOADROW(a, b, d, xin + (size_t)rl * WW);                           \
        h = hcompute(a, b, d);                                             \
    } else { h.h0 = h.h1 = h.h2 = h.h3 = 0.f; }                            \
    vs0 += h.h0 - ring[J].h0;                                              \
    vs1 += h.h1 - ring[J].h1;                                              \
    vs2 += h.h2 - ring[J].h2;                                              \
    vs3 += h.h3 - ring[J].h3;                                              \
    ring[J] = h;                                                           \
    int lo = r - RAD; if (lo < 0) lo = 0;                                  \
    int hi = r + RAD; if (hi > HH - 1) hi = HH - 1;                        \
    float ich = 1.0f / (float)(hi - lo + 1);                               \
    *(float4*)(o + (size_t)r * WW + c) =                                   \
        make_float4(vs0 * ich * sw[0], vs1 * ich * sw[1],                  \
                    vs2 * ich * sw[2], vs3 * ich * sw[3]);                 \
    ++r;                                                                   \
} while (0)

__global__ __launch_bounds__(256, 3)
void box_kernel(const float* __restrict__ x, float* __restrict__ out) {
    const int tid = threadIdx.x;

    // XCD-aware bijective swizzle (768 % 8 == 0): each XCD owns 6 whole
    // images -> adjacent strips share their 9-row halo in the same L2.
    const int lin  = blockIdx.x + NSTRIP * blockIdx.y;
    const int nblk = NSTRIP * gridDim.y;          // 768
    const int cpx  = nblk >> 3;                   // 96
    const int swz  = (lin & 7) * cpx + (lin >> 3);
    const int strip = swz & (NSTRIP - 1);
    const int img   = swz / NSTRIP;

    const int r0 = strip * BH;
    const int c  = tid * 4;
    const bool first = (tid == 0);
    const bool last  = (tid == 255);
    const float4 z4 = make_float4(0.f, 0.f, 0.f, 0.f);

    const float* __restrict__ xin = x + (size_t)img * (HH * WW);
    float* __restrict__ o = out + (size_t)img * (HH * WW);

    // per-column horizontal counts (constant over rows)
    float sw[4];
#pragma unroll
    for (int j = 0; j < 4; ++j) {
        int cc = c + j;
        int lo = cc - RAD < 0 ? 0 : cc - RAD;
        int hi = cc + RAD > WW - 1 ? WW - 1 : cc + RAD;
        sw[j] = 1.0f / (float)(hi - lo + 1);
    }

    // ---- prime: rows r0-5 .. r0+3 into register ring slots 0..8 ----
    HS ring[9];
    float vs0 = 0.f, vs1 = 0.f, vs2 = 0.f, vs3 = 0.f;
#pragma unroll
    for (int k = 0; k < 9; ++k) {
        int rr = r0 - RAD - 1 + k;                // <= r0+3 <= 1023 always
        HS h;
        if (rr >= 0) {
            float4 a, b, d;
            LOADROW(a, b, d, xin + (size_t)rr * WW);
            h = hcompute(a, b, d);
        } else { h.h0 = h.h1 = h.h2 = h.h3 = 0.f; }
        ring[k] = h;
        vs0 += h.h0; vs1 += h.h1; vs2 += h.h2; vs3 += h.h3;
    }

    const bool interior = (r0 >= RAD) && (r0 + BH + RAD <= HH);

    if (interior) {
        const float w0 = sw[0] * (1.0f / 9.0f);
        const float w1 = sw[1] * (1.0f / 9.0f);
        const float w2 = sw[2] * (1.0f / 9.0f);
        const float w3 = sw[3] * (1.0f / 9.0f);

        // prefetch sets 0..2 <- rows r0+4, r0+5, r0+6
        float4 pa0, pb0, pd0, pa1, pb1, pd1, pa2, pb2, pd2;
        const float* rowp = xin + (size_t)(r0 + RAD) * WW;
        LOADROW(pa0, pb0, pd0, rowp); rowp += WW;
        LOADROW(pa1, pb1, pd1, rowp); rowp += WW;
        LOADROW(pa2, pb2, pd2, rowp); rowp += WW;
        // rowp now at row r0+7; each PSTEP prefetches 3 rows ahead.
        // (last 3 steps prefetch rows r0+68..r0+70 <= 966 for interior
        //  strips: in-bounds, harmless, feeds next strip's halo into L2)

        float* op = o + (size_t)r0 * WW;
        // 64 rows = 7 chunks of 9 (ring & pipeline realign each chunk) + 1
#pragma unroll 1
        for (int chunk = 0; chunk < 7; ++chunk) {
            PSTEP(0, 0); PSTEP(1, 1); PSTEP(2, 2);
            PSTEP(3, 0); PSTEP(4, 1); PSTEP(5, 2);
            PSTEP(6, 0); PSTEP(7, 1); PSTEP(8, 2);
        }
        PSTEP(0, 0);
    } else {
        int r = r0;
#pragma unroll 1
        for (int chunk = 0; chunk < 7; ++chunk) {
            GSTEP(0); GSTEP(1); GSTEP(2); GSTEP(3); GSTEP(4);
            GSTEP(5); GSTEP(6); GSTEP(7); GSTEP(8);
        }
        GSTEP(0);
    }
}

extern "C" void kernel_launch(void* const* d_in, const int* in_sizes, int n_in,
                              void* d_out, int out_size, void* d_ws, size_t ws_size,
                              hipStream_t stream) {
    const float* x = (const float*)d_in[0];
    float* out = (float*)d_out;
    int n_images = in_sizes[0] / (HH * WW);   // 16*3 = 48
    dim3 grid(NSTRIP, n_images);              // 16 x 48 = 768 blocks
    dim3 block(256);
    box_kernel<<<grid, block, 0, stream>>>(x, out);
}

// Round 4
// 360.846 us; speedup vs baseline: 1.0747x; 1.0747x over previous
//
#include <hip/hip_runtime.h>

#define HH 1024
#define WW 1024
#define BH 64              // output rows per block -> 16 strips x 48 images = 768 blocks
#define RAD 4
#define NSTRIP (HH / BH)   // 16

struct HS { float h0, h1, h2, h3; };

// 9-wide clipped horizontal sums for 4 consecutive columns.
// window for col c+j: a[j..3] + all of b + d[0..j]  (a = cols c-4..c-1, d = c+4..c+7)
__device__ __forceinline__ HS hcompute(float4 a, float4 b, float4 d) {
    HS h;
    h.h0 = ((a.x + a.y) + (a.z + a.w)) + ((b.x + b.y) + (b.z + b.w)) + d.x;
    h.h1 = h.h0 - a.x + d.y;
    h.h2 = h.h1 - a.y + d.z;
    h.h3 = h.h2 - a.z + d.w;
    return h;
}

__device__ __forceinline__ float shfl1(int addr, float v) {
    return __int_as_float(__builtin_amdgcn_ds_bpermute(addr, __float_as_int(v)));
}

// 3-load halo row (prime only: 9 rows per block, cost amortized)
#define LOADROW(pa, pb, pd, rowptr) do {                                   \
    pb = *(const float4*)((rowptr) + c);                                   \
    pa = first ? z4 : *(const float4*)((rowptr) + c - 4);                  \
    pd = last  ? z4 : *(const float4*)((rowptr) + c + 4);                  \
} while (0)

// prefetch set X <- next row: 1 float4 + masked 16B edge-halo load
#define PFETCH(X) do {                                                     \
    pb##X = *(const float4*)(rowp + c);                                    \
    if (eAny) pe##X = *(const float4*)(rowp + eoff);                       \
    rowp += WW;                                                            \
} while (0)

// boundary variant: clamp prefetch row (validity handled at consume)
#define PFETCHB(X) do {                                                    \
    const float* rp = xin + (size_t)(pr < HH ? pr : (HH - 1)) * WW;        \
    pb##X = *(const float4*)(rp + c);                                      \
    if (eAny) pe##X = *(const float4*)(rp + eoff);                         \
    ++pr;                                                                  \
} while (0)

// shared consume core: rebuild a/d from lane+-1 bpermute + edge regs
#define BUILD_AD()                                                         \
    float4 a, d;                                                           \
    a.x = shfl1(addrU, b.x); a.y = shfl1(addrU, b.y);                      \
    a.z = shfl1(addrU, b.z); a.w = shfl1(addrU, b.w);                      \
    d.x = shfl1(addrD, b.x); d.y = shfl1(addrD, b.y);                      \
    d.z = shfl1(addrD, b.z); d.w = shfl1(addrD, b.w);                      \
    if (lane == 0)  a = first ? z4 : pev;                                  \
    if (lane == 63) d = last  ? z4 : pev;

// interior step: J = ring slot (static), PX = prefetch set (static)
#define ISTEP(J, PX) do {                                                  \
    float4 b   = pb##PX;                                                   \
    float4 pev = pe##PX;                                                   \
    PFETCH(PX);                       /* issue next load ASAP */           \
    BUILD_AD();                                                            \
    HS h = hcompute(a, b, d);                                              \
    float4 hold = hring[J][tid];                                           \
    vs0 += h.h0 - hold.x; vs1 += h.h1 - hold.y;                            \
    vs2 += h.h2 - hold.z; vs3 += h.h3 - hold.w;                            \
    hring[J][tid] = make_float4(h.h0, h.h1, h.h2, h.h3);                   \
    *(float4*)op = make_float4(vs0 * w0, vs1 * w1, vs2 * w2, vs3 * w3);    \
    op += WW;                                                              \
} while (0)

// boundary step: + row-validity zeroing and per-row vertical count
#define BSTEP(J, PX) do {                                                  \
    float4 b   = pb##PX;                                                   \
    float4 pev = pe##PX;                                                   \
    PFETCHB(PX);                                                           \
    BUILD_AD();                                                            \
    HS h = hcompute(a, b, d);                                              \
    bool valid = (r + RAD) < HH;                                           \
    h.h0 = valid ? h.h0 : 0.f; h.h1 = valid ? h.h1 : 0.f;                  \
    h.h2 = valid ? h.h2 : 0.f; h.h3 = valid ? h.h3 : 0.f;                  \
    float4 hold = hring[J][tid];                                           \
    vs0 += h.h0 - hold.x; vs1 += h.h1 - hold.y;                            \
    vs2 += h.h2 - hold.z; vs3 += h.h3 - hold.w;                            \
    hring[J][tid] = make_float4(h.h0, h.h1, h.h2, h.h3);                   \
    int lo = r - RAD; lo = lo < 0 ? 0 : lo;                                \
    int hi = r + RAD; hi = hi > HH - 1 ? HH - 1 : hi;                      \
    float ich = 1.0f / (float)(hi - lo + 1);                               \
    *(float4*)op = make_float4(vs0 * ich * sw[0], vs1 * ich * sw[1],       \
                               vs2 * ich * sw[2], vs3 * ich * sw[3]);      \
    op += WW; ++r;                                                         \
} while (0)

// 18 = LCM(9 ring slots, 6 prefetch sets); steps i: J=i%9, PX=i%6
#define CHUNK18(STEP)                                                      \
    STEP(0,0); STEP(1,1); STEP(2,2); STEP(3,3); STEP(4,4); STEP(5,5);      \
    STEP(6,0); STEP(7,1); STEP(8,2); STEP(0,3); STEP(1,4); STEP(2,5);      \
    STEP(3,0); STEP(4,1); STEP(5,2); STEP(6,3); STEP(7,4); STEP(8,5);
#define TAIL10(STEP)                                                       \
    STEP(0,0); STEP(1,1); STEP(2,2); STEP(3,3); STEP(4,4);                 \
    STEP(5,5); STEP(6,0); STEP(7,1); STEP(8,2); STEP(0,3);

__global__ __launch_bounds__(256)
__attribute__((amdgpu_waves_per_eu(3, 3)))   // grid = exactly 3 blocks/CU; don't
                                             // let the allocator chase 8 waves/EU
void box_kernel(const float* __restrict__ x, float* __restrict__ out) {
    __shared__ float4 hring[9][256];   // 36 KB; every slot private to its thread

    const int tid = threadIdx.x;

    // XCD-aware bijective swizzle (768 % 8 == 0)
    const int lin  = blockIdx.x + NSTRIP * blockIdx.y;
    const int nblk = NSTRIP * gridDim.y;
    const int cpx  = nblk >> 3;
    const int swz  = (lin & 7) * cpx + (lin >> 3);
    const int strip = swz & (NSTRIP - 1);
    const int img   = swz / NSTRIP;

    const int r0 = strip * BH;
    const int c  = tid * 4;
    const int lane = tid & 63;
    const bool first = (tid == 0);
    const bool last  = (tid == 255);
    const float4 z4 = make_float4(0.f, 0.f, 0.f, 0.f);

    // bpermute byte addresses for lane-1 / lane+1 (wave-local)
    const int addrU = ((lane - 1) & 63) << 2;
    const int addrD = ((lane + 1) & 63) << 2;

    // wave-edge halo lanes: lane 0 needs cols c-4.., lane 63 needs c+4..
    const bool eLo  = (lane == 0)  && !first;
    const bool eHi  = (lane == 63) && !last;
    const bool eAny = eLo || eHi;
    const int  eoff = eLo ? (c - 4) : (c + 4);

    const float* __restrict__ xin = x + (size_t)img * (HH * WW);
    float* __restrict__ o = out + (size_t)img * (HH * WW);

    // per-column horizontal counts (constant over rows)
    float sw[4];
#pragma unroll
    for (int j = 0; j < 4; ++j) {
        int cc = c + j;
        int lo = cc - RAD < 0 ? 0 : cc - RAD;
        int hi = cc + RAD > WW - 1 ? WW - 1 : cc + RAD;
        sw[j] = 1.0f / (float)(hi - lo + 1);
    }

    // ---- prime: rows r0-5 .. r0+3 -> ring slots 0..8 (3-load halo, one-time)
    float vs0 = 0.f, vs1 = 0.f, vs2 = 0.f, vs3 = 0.f;
#pragma unroll
    for (int k = 0; k < 9; ++k) {
        int rr = r0 - RAD - 1 + k;               // <= r0+3 <= 1023 always
        HS h;
        if (rr >= 0) {
            float4 a, b, d;
            LOADROW(a, b, d, xin + (size_t)rr * WW);
            h = hcompute(a, b, d);
        } else { h.h0 = h.h1 = h.h2 = h.h3 = 0.f; }
        hring[k][tid] = make_float4(h.h0, h.h1, h.h2, h.h3);
        vs0 += h.h0; vs1 += h.h1; vs2 += h.h2; vs3 += h.h3;
    }

    const bool interior = (r0 >= RAD) && (r0 + BH + RAD <= HH);

    float4 pb0, pb1, pb2, pb3, pb4, pb5;
    float4 pe0 = z4, pe1 = z4, pe2 = z4, pe3 = z4, pe4 = z4, pe5 = z4;
    float* op = o + (size_t)r0 * WW + c;

    if (interior) {
        const float w0 = sw[0] * (1.0f / 9.0f);
        const float w1 = sw[1] * (1.0f / 9.0f);
        const float w2 = sw[2] * (1.0f / 9.0f);
        const float w3 = sw[3] * (1.0f / 9.0f);

        // prefetch rows r0+4 .. r0+9 into sets 0..5
        const float* rowp = xin + (size_t)(r0 + RAD) * WW;
        PFETCH(0); PFETCH(1); PFETCH(2); PFETCH(3); PFETCH(4); PFETCH(5);
        // steady state: consume row r -> reissue row r+10; max touched row
        // for last interior strip (r0=896): 896+73 = 969 < 1024. safe.

#pragma unroll 1
        for (int chunk = 0; chunk < 3; ++chunk) {   // 3*18 = 54 rows
            CHUNK18(ISTEP)
        }
        TAIL10(ISTEP)                                // rows 54..63
    } else {
        // boundary strips (2 of 16): same 6-deep pipeline, clamped loads,
        // per-row vertical count, h zeroed for rows >= HH.
        int r = r0;
        int pr = r0 + RAD;
        PFETCHB(0); PFETCHB(1); PFETCHB(2); PFETCHB(3); PFETCHB(4); PFETCHB(5);

#pragma unroll 1
        for (int chunk = 0; chunk < 3; ++chunk) {
            CHUNK18(BSTEP)
        }
        TAIL10(BSTEP)
    }
}

extern "C" void kernel_launch(void* const* d_in, const int* in_sizes, int n_in,
                              void* d_out, int out_size, void* d_ws, size_t ws_size,
                              hipStream_t stream) {
    const float* x = (const float*)d_in[0];
    float* out = (float*)d_out;
    int n_images = in_sizes[0] / (HH * WW);   // 16*3 = 48
    dim3 grid(NSTRIP, n_images);              // 16 x 48 = 768 blocks
    dim3 block(256);
    box_kernel<<<grid, block, 0, stream>>>(x, out);
}